// Round 1
// baseline (9471.001 us; speedup 1.0000x reference)
//
#include <hip/hip_runtime.h>

// Residual 2-layer LSTM, T=256 B=64 H=1024, fp32 io, bf16 MFMA compute.
// Strategy: persistent kernel per layer, 128 WGs x 256 thr. Each WG owns 8 h-cols
// (32 gate cols). Weights held in VGPRs as persistent MFMA B-fragments.
// Waves 0-1: x-part of K (no dep). Waves 2-3: h-part, gated on per-step flags.
// h history stored full-length (no slot reuse) in WG-blocked layout -> no stale
// L2 lines, disjoint 1KB aligned writes per WG (no cross-XCD partial-line risk).

#define TT 256
#define BB 64
#define HH 1024
#define GG 128
#define BH (BB * HH) // 65536 elements per timestep

typedef __attribute__((ext_vector_type(8))) short short8;
typedef __attribute__((ext_vector_type(4))) float float4v;

__device__ __forceinline__ unsigned short f2bf(float f) {
  unsigned u = __builtin_bit_cast(unsigned, f);
  u += 0x7fffu + ((u >> 16) & 1u);
  return (unsigned short)(u >> 16);
}
__device__ __forceinline__ float bf2f(unsigned short s) {
  unsigned u = ((unsigned)s) << 16;
  return __builtin_bit_cast(float, u);
}
__device__ __forceinline__ float fexp2(float x) { return __builtin_amdgcn_exp2f(x); }
__device__ __forceinline__ float frcp(float x) { return __builtin_amdgcn_rcpf(x); }
// sigmoid(x) = 1/(1+2^(-x/ln2)); safe at +-inf
__device__ __forceinline__ float sigm(float x) {
  return frcp(1.0f + fexp2(-1.4426950408889634f * x));
}
// tanh(x) = 1 - 2/(1+e^{2x}); safe at +-inf (no inf/inf)
__device__ __forceinline__ float tanha(float x) {
  return 1.0f - 2.0f * frcp(1.0f + fexp2(2.8853900817779268f * x));
}

__global__ __launch_bounds__(256) void cvt_f32_bf16(const float* __restrict__ in,
                                                    unsigned short* __restrict__ out,
                                                    int n8) {
  int i = blockIdx.x * 256 + threadIdx.x;
  if (i >= n8) return;
  const float4v* p = (const float4v*)in + (size_t)i * 2;
  float4v a = p[0], b = p[1];
  short8 v;
  v[0] = (short)f2bf(a[0]); v[1] = (short)f2bf(a[1]);
  v[2] = (short)f2bf(a[2]); v[3] = (short)f2bf(a[3]);
  v[4] = (short)f2bf(b[0]); v[5] = (short)f2bf(b[1]);
  v[6] = (short)f2bf(b[2]); v[7] = (short)f2bf(b[3]);
  ((short8*)out)[i] = v;
}

// Ax: input activations (bf16). xlayout==0: row-major [t][b][h] (layer5: xb).
// xlayout==1: blocked [t][col>>3][b][col&7] (layer6: out5b, same layout as hbuf).
// hbuf: [t][col>>3][b][col&7] bf16, full history (no slot reuse within a launch).
// flags: [t][wg] int, pre-zeroed.
__global__ __launch_bounds__(256, 1) void lstm_layer(
    const unsigned short* __restrict__ Ax, const int xlayout,
    const float* __restrict__ wih, const float* __restrict__ whh,
    const float* __restrict__ bih, const float* __restrict__ bhh,
    const float* __restrict__ resf,          // fp32 row-major residual (layer5: x) or null
    const unsigned short* __restrict__ resb, // bf16 blocked residual (layer6: out5b) or null
    unsigned short* __restrict__ outb,       // bf16 blocked out (layer5: out5b) or null
    float* __restrict__ outf,                // fp32 row-major out (layer6: d_out) or null
    unsigned short* __restrict__ hbuf, int* __restrict__ flags) {
  const int p = blockIdx.x;
  const int tid = threadIdx.x;
  const int w = tid >> 6;    // wave 0..3
  const int lane = tid & 63;
  const int ln = lane & 15;  // MFMA n/m lane index
  const int q = lane >> 4;   // MFMA k-quad
  const bool is_h = (w >= 2);
  const int kq = is_h ? (w - 2) : w; // k-quarter within the 1024-wide matrix

  __shared__ float gp[4][BB][33]; // per-wave partial gates [wave][b][n], padded

  // ---- persistent weight fragments in VGPRs: wf[kk*2+nt], n = 16*nt+ln,
  // k = kq*512 + kk*32 + 8*q + j  (j=0..7 contiguous)
  const float* wmat = is_h ? whh : wih;
  short8 wf[32];
#pragma unroll
  for (int kk = 0; kk < 16; ++kk) {
#pragma unroll
    for (int nt = 0; nt < 2; ++nt) {
      const int n = 16 * nt + ln;
      const int gidx = (n >> 3) * HH + p * 8 + (n & 7); // gate order i,f,g,o
      const float* src = wmat + (size_t)gidx * HH + kq * 512 + kk * 32 + 8 * q;
      short8 v;
#pragma unroll
      for (int j = 0; j < 8; ++j) v[j] = (short)f2bf(src[j]);
      wf[kk * 2 + nt] = v;
    }
  }

  // ---- per-thread elementwise state: owns (b=eb, jj0) and (b=eb, jj0+4)
  const int eb = tid & 63;
  const int jj0 = tid >> 6; // 0..3
  float bsum[2][4];
#pragma unroll
  for (int s = 0; s < 2; ++s) {
    const int jj = jj0 + 4 * s;
#pragma unroll
    for (int gt = 0; gt < 4; ++gt) {
      const int gidx = gt * HH + p * 8 + jj;
      bsum[s][gt] = bih[gidx] + bhh[gidx];
    }
  }
  float cst[2] = {0.f, 0.f};

  // ---- A-operand addressing (per lane, per m-tile)
  size_t row_off[4];
  size_t kstep;
  if (!is_h && xlayout == 0) {
    kstep = 32; // row-major: [b][k]
#pragma unroll
    for (int mt = 0; mt < 4; ++mt)
      row_off[mt] = (size_t)(16 * mt + ln) * HH + (size_t)(kq * 512 + 8 * q);
  } else {
    kstep = 32 * 64; // blocked: elem offset = k*64 + b*8 (k multiple of 8)
#pragma unroll
    for (int mt = 0; mt < 4; ++mt)
      row_off[mt] = (size_t)(16 * mt + ln) * 8 + (size_t)(kq * 512 + 8 * q) * 64;
  }

  for (int t = 0; t < TT; ++t) {
    float4v acc[4][2];
#pragma unroll
    for (int mt = 0; mt < 4; ++mt)
#pragma unroll
      for (int nt = 0; nt < 2; ++nt)
        acc[mt][nt] = (float4v){0.f, 0.f, 0.f, 0.f};

    const unsigned short* Abase = nullptr;
    bool doit = true;
    if (!is_h) {
      Abase = Ax + (size_t)t * BH;
    } else if (t == 0) {
      doit = false; // h_{-1} = 0
    } else {
      // wait for all 128 WGs to have published h[t-1]
      int* fl = flags + (size_t)(t - 1) * GG;
      for (;;) {
        const int a0 = __hip_atomic_load(fl + lane, __ATOMIC_RELAXED, __HIP_MEMORY_SCOPE_AGENT);
        const int a1 = __hip_atomic_load(fl + 64 + lane, __ATOMIC_RELAXED, __HIP_MEMORY_SCOPE_AGENT);
        if (__all((a0 != 0) & (a1 != 0))) break;
        __builtin_amdgcn_s_sleep(1);
      }
      __builtin_amdgcn_fence(__ATOMIC_ACQUIRE, "agent");
      Abase = hbuf + (size_t)(t - 1) * BH;
    }

    if (doit) {
#pragma unroll
      for (int kk = 0; kk < 16; ++kk) {
        short8 af[4];
#pragma unroll
        for (int mt = 0; mt < 4; ++mt)
          af[mt] = *(const short8*)(Abase + row_off[mt] + (size_t)kk * kstep);
#pragma unroll
        for (int mt = 0; mt < 4; ++mt) {
          acc[mt][0] = __builtin_amdgcn_mfma_f32_16x16x32_bf16(af[mt], wf[kk * 2 + 0], acc[mt][0], 0, 0, 0);
          acc[mt][1] = __builtin_amdgcn_mfma_f32_16x16x32_bf16(af[mt], wf[kk * 2 + 1], acc[mt][1], 0, 0, 0);
        }
      }
    }

    // C layout: row m = 16*mt + 4*q + r, col n = 16*nt + ln
#pragma unroll
    for (int mt = 0; mt < 4; ++mt)
#pragma unroll
      for (int nt = 0; nt < 2; ++nt)
#pragma unroll
        for (int r = 0; r < 4; ++r)
          gp[w][16 * mt + 4 * q + r][16 * nt + ln] = acc[mt][nt][r];

    __syncthreads();

    {
      const size_t tb = (size_t)t * BH;
#pragma unroll
      for (int s = 0; s < 2; ++s) {
        const int jj = jj0 + 4 * s;
        float iv = bsum[s][0], fv = bsum[s][1], gv = bsum[s][2], ov = bsum[s][3];
#pragma unroll
        for (int ww = 0; ww < 4; ++ww) {
          iv += gp[ww][eb][jj];
          fv += gp[ww][eb][8 + jj];
          gv += gp[ww][eb][16 + jj];
          ov += gp[ww][eb][24 + jj];
        }
        const float ig = sigm(iv);
        const float fg = sigm(fv);
        const float gg_ = tanha(gv);
        const float og = sigm(ov);
        const float c = fg * cst[s] + ig * gg_;
        cst[s] = c;
        const float h = og * tanha(c);
        // publish h (blocked layout, own 1KB-aligned region)
        hbuf[tb + (size_t)p * 512 + (size_t)eb * 8 + jj] = f2bf(h);
        float o;
        if (resf) o = h + resf[tb + (size_t)eb * HH + p * 8 + jj];
        else      o = h + bf2f(resb[tb + (size_t)p * 512 + (size_t)eb * 8 + jj]);
        if (outb) outb[tb + (size_t)p * 512 + (size_t)eb * 8 + jj] = f2bf(o);
        if (outf) outf[tb + (size_t)eb * HH + p * 8 + jj] = o;
      }
    }

    __syncthreads(); // drains all waves' h stores to L2 (vmcnt0 before barrier)

    if (tid == 0) {
      __builtin_amdgcn_fence(__ATOMIC_RELEASE, "agent"); // wbl2 -> LLC
      __hip_atomic_store(flags + (size_t)t * GG + p, 1, __ATOMIC_RELAXED, __HIP_MEMORY_SCOPE_AGENT);
    }
  }
}

extern "C" void kernel_launch(void* const* d_in, const int* in_sizes, int n_in,
                              void* d_out, int out_size, void* d_ws, size_t ws_size,
                              hipStream_t stream) {
  const float* x    = (const float*)d_in[0];
  const float* wih5 = (const float*)d_in[1];
  const float* whh5 = (const float*)d_in[2];
  const float* bih5 = (const float*)d_in[3];
  const float* bhh5 = (const float*)d_in[4];
  const float* wih6 = (const float*)d_in[5];
  const float* whh6 = (const float*)d_in[6];
  const float* bih6 = (const float*)d_in[7];
  const float* bhh6 = (const float*)d_in[8];
  float* out = (float*)d_out;

  // workspace layout (needs ~96.3 MB):
  //   [0, 32MB)   xb    : x as bf16, row-major
  //   [32, 64MB)  out5b : layer5 output (h5+x) bf16, blocked layout
  //   [64, 96MB)  hbuf  : h history bf16, blocked layout (shared by both layers)
  //   [96MB, +256KB) flags : 2 layers * 256 steps * 128 WGs
  char* ws = (char*)d_ws;
  unsigned short* xb    = (unsigned short*)(ws);
  unsigned short* out5b = (unsigned short*)(ws + 33554432);
  unsigned short* hbuf  = (unsigned short*)(ws + 67108864);
  int* flags            = (int*)(ws + 100663296);

  hipMemsetAsync(flags, 0, 2 * TT * GG * sizeof(int), stream);

  const int n8 = TT * BB * HH / 8;
  cvt_f32_bf16<<<dim3((n8 + 255) / 256), dim3(256), 0, stream>>>(x, xb, n8);

  lstm_layer<<<dim3(GG), dim3(256), 0, stream>>>(
      xb, 0, wih5, whh5, bih5, bhh5, x, nullptr, out5b, nullptr, hbuf, flags);
  lstm_layer<<<dim3(GG), dim3(256), 0, stream>>>(
      out5b, 1, wih6, whh6, bih6, bhh6, nullptr, out5b, nullptr, out, hbuf,
      flags + TT * GG);
}

// Round 2
// 7752.943 us; speedup vs baseline: 1.2216x; 1.2216x over previous
//
#include <hip/hip_runtime.h>

// Residual 2-layer LSTM, T=256 B=64 H=1024, fp32 io, bf16 MFMA compute.
// Persistent kernel per layer, 128 WGs x 256 thr. Each WG owns 8 h-cols
// (32 gate cols). Weights live in VGPRs as persistent MFMA B-fragments.
// Waves 0-1: x-part of K (no dep). Waves 2-3: h-part, gated on per-step flags.
//
// R2 change: NO agent-scope fences in the per-step path (R1 showed they emit
// buffer_wbl2/buffer_inv -> whole-L2 writeback+invalidate per WG per step ->
// 18.5us/step, MfmaUtil 2.3%). All cross-WG h traffic now uses relaxed
// agent-scope atomics (coherent point directly); publisher drains vmcnt
// explicitly then sets flag relaxed. R1 proved relaxed agent atomics are
// cross-XCD coherent with no fence (poll loop worked pre-fence).

#define TT 256
#define BB 64
#define HH 1024
#define GG 128
#define BH (BB * HH) // 65536 elements per timestep

typedef __attribute__((ext_vector_type(8))) short short8;
typedef __attribute__((ext_vector_type(4))) float float4v;
typedef __attribute__((ext_vector_type(2))) float float2v;
typedef __attribute__((ext_vector_type(4))) unsigned int uint4v;

__device__ __forceinline__ unsigned short f2bf(float f) {
  unsigned u = __builtin_bit_cast(unsigned, f);
  u += 0x7fffu + ((u >> 16) & 1u);
  return (unsigned short)(u >> 16);
}
__device__ __forceinline__ float bf2f(unsigned short s) {
  unsigned u = ((unsigned)s) << 16;
  return __builtin_bit_cast(float, u);
}
__device__ __forceinline__ float fexp2(float x) { return __builtin_amdgcn_exp2f(x); }
__device__ __forceinline__ float frcp(float x) { return __builtin_amdgcn_rcpf(x); }
__device__ __forceinline__ float sigm(float x) {
  return frcp(1.0f + fexp2(-1.4426950408889634f * x));
}
__device__ __forceinline__ float tanha(float x) {
  return 1.0f - 2.0f * frcp(1.0f + fexp2(2.8853900817779268f * x));
}

// 16B h-fragment read via 4 coherent (agent-scope) dword loads; bypasses any
// stale XCD-L2 state, no acquire fence needed (in-order VMEM issue per wave +
// flag observed at coherent point => data at coherent point).
__device__ __forceinline__ short8 load_h16(const unsigned short* p) {
  unsigned int* q = (unsigned int*)p;
  uint4v u;
#pragma unroll
  for (int i = 0; i < 4; ++i)
    u[i] = __hip_atomic_load(q + i, __ATOMIC_RELAXED, __HIP_MEMORY_SCOPE_AGENT);
  return __builtin_bit_cast(short8, u);
}

__global__ __launch_bounds__(256) void cvt_f32_bf16(const float* __restrict__ in,
                                                    unsigned short* __restrict__ out,
                                                    int n8) {
  int i = blockIdx.x * 256 + threadIdx.x;
  if (i >= n8) return;
  const float4v* p = (const float4v*)in + (size_t)i * 2;
  float4v a = p[0], b = p[1];
  short8 v;
  v[0] = (short)f2bf(a[0]); v[1] = (short)f2bf(a[1]);
  v[2] = (short)f2bf(a[2]); v[3] = (short)f2bf(a[3]);
  v[4] = (short)f2bf(b[0]); v[5] = (short)f2bf(b[1]);
  v[6] = (short)f2bf(b[2]); v[7] = (short)f2bf(b[3]);
  ((short8*)out)[i] = v;
}

// Ax layouts: 0 = row-major [t][b][h] (layer5 xb); 1 = blocked
// [t][col>>3][b][col&7] (layer6 reads out5b, same layout as hbuf).
__global__ __launch_bounds__(256, 1) void lstm_layer(
    const unsigned short* __restrict__ Ax, const int xlayout,
    const float* __restrict__ wih, const float* __restrict__ whh,
    const float* __restrict__ bih, const float* __restrict__ bhh,
    const float* __restrict__ resf,          // fp32 row-major residual or null
    const unsigned short* __restrict__ resb, // bf16 blocked residual or null
    unsigned short* __restrict__ outb,       // bf16 blocked out or null
    float* __restrict__ outf,                // fp32 row-major out or null
    unsigned short* __restrict__ hbuf, int* __restrict__ flags) {
  const int p = blockIdx.x;
  const int tid = threadIdx.x;
  const int w = tid >> 6;
  const int lane = tid & 63;
  const int ln = lane & 15;
  const int q = lane >> 4;
  const bool is_h = (w >= 2);
  const int kq = is_h ? (w - 2) : w;

  // stride 35: writes (12q+ln)%32 <=2-way, reads (3*eb)%32 <=2-way (free)
  __shared__ float gp[4][BB][35];

  // persistent weight fragments: wf[kk*2+nt], n = 16*nt+ln,
  // k = kq*512 + kk*32 + 8*q + j
  const float* wmat = is_h ? whh : wih;
  short8 wf[32];
#pragma unroll
  for (int kk = 0; kk < 16; ++kk) {
#pragma unroll
    for (int nt = 0; nt < 2; ++nt) {
      const int n = 16 * nt + ln;
      const int gidx = (n >> 3) * HH + p * 8 + (n & 7); // gate order i,f,g,o
      const float* src = wmat + (size_t)gidx * HH + kq * 512 + kk * 32 + 8 * q;
      short8 v;
#pragma unroll
      for (int j = 0; j < 8; ++j) v[j] = (short)f2bf(src[j]);
      wf[kk * 2 + nt] = v;
    }
  }

  // elementwise state: thread owns (b=eb, jj) for jj = 2*jj0 + {0,1} (adjacent!)
  const int eb = tid & 63;
  const int jj0 = tid >> 6; // 0..3
  float bsum[2][4];
#pragma unroll
  for (int s = 0; s < 2; ++s) {
    const int jj = 2 * jj0 + s;
#pragma unroll
    for (int gt = 0; gt < 4; ++gt) {
      const int gidx = gt * HH + p * 8 + jj;
      bsum[s][gt] = bih[gidx] + bhh[gidx];
    }
  }
  float cst[2] = {0.f, 0.f};

  size_t row_off[4];
  size_t kstep;
  if (!is_h && xlayout == 0) {
    kstep = 32;
#pragma unroll
    for (int mt = 0; mt < 4; ++mt)
      row_off[mt] = (size_t)(16 * mt + ln) * HH + (size_t)(kq * 512 + 8 * q);
  } else {
    kstep = 32 * 64; // blocked: elem offset = k*64 + b*8
#pragma unroll
    for (int mt = 0; mt < 4; ++mt)
      row_off[mt] = (size_t)(16 * mt + ln) * 8 + (size_t)(kq * 512 + 8 * q) * 64;
  }

  for (int t = 0; t < TT; ++t) {
    float4v acc[4][2];
#pragma unroll
    for (int mt = 0; mt < 4; ++mt)
#pragma unroll
      for (int nt = 0; nt < 2; ++nt)
        acc[mt][nt] = (float4v){0.f, 0.f, 0.f, 0.f};

    if (!is_h) {
      const unsigned short* Abase = Ax + (size_t)t * BH;
#pragma unroll
      for (int kk = 0; kk < 16; ++kk) {
        short8 af[4];
#pragma unroll
        for (int mt = 0; mt < 4; ++mt)
          af[mt] = *(const short8*)(Abase + row_off[mt] + (size_t)kk * kstep);
#pragma unroll
        for (int mt = 0; mt < 4; ++mt) {
          acc[mt][0] = __builtin_amdgcn_mfma_f32_16x16x32_bf16(af[mt], wf[kk * 2 + 0], acc[mt][0], 0, 0, 0);
          acc[mt][1] = __builtin_amdgcn_mfma_f32_16x16x32_bf16(af[mt], wf[kk * 2 + 1], acc[mt][1], 0, 0, 0);
        }
      }
    } else if (t > 0) {
      // wait for all 128 WGs to publish h[t-1]
      int* fl = flags + (size_t)(t - 1) * GG;
      for (;;) {
        const int a0 = __hip_atomic_load(fl + lane, __ATOMIC_RELAXED, __HIP_MEMORY_SCOPE_AGENT);
        const int a1 = __hip_atomic_load(fl + 64 + lane, __ATOMIC_RELAXED, __HIP_MEMORY_SCOPE_AGENT);
        if (__all((a0 != 0) & (a1 != 0))) break;
        __builtin_amdgcn_s_sleep(1);
      }
      // compiler ordering only; workgroup scope => no L2 cache ops
      __builtin_amdgcn_fence(__ATOMIC_ACQUIRE, "workgroup");
      const unsigned short* Abase = hbuf + (size_t)(t - 1) * BH;
#pragma unroll
      for (int kk = 0; kk < 16; ++kk) {
        short8 af[4];
#pragma unroll
        for (int mt = 0; mt < 4; ++mt)
          af[mt] = load_h16(Abase + row_off[mt] + (size_t)kk * kstep);
#pragma unroll
        for (int mt = 0; mt < 4; ++mt) {
          acc[mt][0] = __builtin_amdgcn_mfma_f32_16x16x32_bf16(af[mt], wf[kk * 2 + 0], acc[mt][0], 0, 0, 0);
          acc[mt][1] = __builtin_amdgcn_mfma_f32_16x16x32_bf16(af[mt], wf[kk * 2 + 1], acc[mt][1], 0, 0, 0);
        }
      }
    }

    // C layout: row m = 16*mt + 4*q + r, col n = 16*nt + ln
#pragma unroll
    for (int mt = 0; mt < 4; ++mt)
#pragma unroll
      for (int nt = 0; nt < 2; ++nt)
#pragma unroll
        for (int r = 0; r < 4; ++r)
          gp[w][16 * mt + 4 * q + r][16 * nt + ln] = acc[mt][nt][r];

    __syncthreads();

    {
      const size_t tb = (size_t)t * BH;
      float hv[2], ov_[2];
#pragma unroll
      for (int s = 0; s < 2; ++s) {
        const int jj = 2 * jj0 + s;
        float iv = bsum[s][0], fv = bsum[s][1], gv = bsum[s][2], ov = bsum[s][3];
#pragma unroll
        for (int ww = 0; ww < 4; ++ww) {
          iv += gp[ww][eb][jj];
          fv += gp[ww][eb][8 + jj];
          gv += gp[ww][eb][16 + jj];
          ov += gp[ww][eb][24 + jj];
        }
        const float ig = sigm(iv);
        const float fg = sigm(fv);
        const float gg_ = tanha(gv);
        const float og = sigm(ov);
        const float c = fg * cst[s] + ig * gg_;
        cst[s] = c;
        hv[s] = og * tanha(c);
      }
      // publish h: packed 2xbf16 -> one coherent 4B store
      const size_t hidx = tb + (size_t)p * 512 + (size_t)eb * 8 + 2 * jj0;
      unsigned packed = (unsigned)f2bf(hv[0]) | ((unsigned)f2bf(hv[1]) << 16);
      __hip_atomic_store((unsigned*)(hbuf + hidx), packed, __ATOMIC_RELAXED,
                         __HIP_MEMORY_SCOPE_AGENT);
      // residual + output (ordinary cached stores; flushed at kernel end)
      if (resf) {
        const float2v r = *(const float2v*)(resf + tb + (size_t)eb * HH + p * 8 + 2 * jj0);
        ov_[0] = hv[0] + r[0];
        ov_[1] = hv[1] + r[1];
      } else {
        const unsigned rb = *(const unsigned*)(resb + hidx);
        ov_[0] = hv[0] + bf2f((unsigned short)(rb & 0xffff));
        ov_[1] = hv[1] + bf2f((unsigned short)(rb >> 16));
      }
      if (outb) {
        unsigned po = (unsigned)f2bf(ov_[0]) | ((unsigned)f2bf(ov_[1]) << 16);
        *(unsigned*)(outb + hidx) = po;
      }
      if (outf) {
        float2v vo;
        vo[0] = ov_[0];
        vo[1] = ov_[1];
        *(float2v*)(outf + tb + (size_t)eb * HH + p * 8 + 2 * jj0) = vo;
      }
    }

    // drain this wave's h stores to the coherent point, then flag.
    asm volatile("s_waitcnt vmcnt(0)" ::: "memory");
    __syncthreads(); // all waves drained past this point
    if (tid == 0)
      __hip_atomic_store(flags + (size_t)t * GG + p, 1, __ATOMIC_RELAXED,
                         __HIP_MEMORY_SCOPE_AGENT);
  }
}

extern "C" void kernel_launch(void* const* d_in, const int* in_sizes, int n_in,
                              void* d_out, int out_size, void* d_ws, size_t ws_size,
                              hipStream_t stream) {
  const float* x    = (const float*)d_in[0];
  const float* wih5 = (const float*)d_in[1];
  const float* whh5 = (const float*)d_in[2];
  const float* bih5 = (const float*)d_in[3];
  const float* bhh5 = (const float*)d_in[4];
  const float* wih6 = (const float*)d_in[5];
  const float* whh6 = (const float*)d_in[6];
  const float* bih6 = (const float*)d_in[7];
  const float* bhh6 = (const float*)d_in[8];
  float* out = (float*)d_out;

  // workspace: [0,32M) xb ; [32M,64M) out5b ; [64M,96M) hbuf ; [96M,+256K) flags
  char* ws = (char*)d_ws;
  unsigned short* xb    = (unsigned short*)(ws);
  unsigned short* out5b = (unsigned short*)(ws + 33554432);
  unsigned short* hbuf  = (unsigned short*)(ws + 67108864);
  int* flags            = (int*)(ws + 100663296);

  hipMemsetAsync(flags, 0, 2 * TT * GG * sizeof(int), stream);

  const int n8 = TT * BB * HH / 8;
  cvt_f32_bf16<<<dim3((n8 + 255) / 256), dim3(256), 0, stream>>>(x, xb, n8);

  lstm_layer<<<dim3(GG), dim3(256), 0, stream>>>(
      xb, 0, wih5, whh5, bih5, bhh5, x, nullptr, out5b, nullptr, hbuf, flags);
  lstm_layer<<<dim3(GG), dim3(256), 0, stream>>>(
      out5b, 1, wih6, whh6, bih6, bhh6, nullptr, out5b, nullptr, out, hbuf,
      flags + TT * GG);
}

// Round 3
// 4966.148 us; speedup vs baseline: 1.9071x; 1.5612x over previous
//
#include <hip/hip_runtime.h>

// Residual 2-layer LSTM, T=256 B=64 H=1024, fp32 io, bf16 MFMA compute.
// Persistent kernel per layer, 128 WGs x 256 thr, 1 WG/CU. Each WG owns 8
// h-cols (32 gate cols). Weights live in VGPRs (wfx+wfh = 128 VGPRs/lane).
// All 4 waves split BOTH x-K and h-K 4 ways (K=256 each, 8 kk iters).
//
// R3 changes vs R2 (which was 15.7us/step, MfmaUtil 2.7%):
//  - h reads are NORMAL CACHED loads. hbuf addresses are virgin within a
//    kernel (full-history, written once agent-scope -> LLC, read after), so
//    a cached load must miss XCD-L2 and pull the fresh line from LLC, then
//    L2-multicasts to the other 15 WGs on that XCD. R2's uncached reads cost
//    16MB/step of LLC traffic + un-pipelineable 700-900cyc chains.
//    Layer 6 gets its OWN hbuf (reuses xb region; dispatch-start L2
//    invalidate clears layer-5's cached xb lines - proven by R2's out5b path).
//  - K split 4-ways across all waves: h-GEMM serial chain halves.
//  - Only wave 0 polls flags (+s_sleep backoff): 4x less LLC poll traffic.
//  - Flag raised before the residual/output tail (off critical path).

#define TT 256
#define BB 64
#define HH 1024
#define GG 128
#define BH (BB * HH)

typedef __attribute__((ext_vector_type(8))) short short8;
typedef __attribute__((ext_vector_type(4))) float float4v;
typedef __attribute__((ext_vector_type(2))) float float2v;

__device__ __forceinline__ unsigned short f2bf(float f) {
  unsigned u = __builtin_bit_cast(unsigned, f);
  u += 0x7fffu + ((u >> 16) & 1u);
  return (unsigned short)(u >> 16);
}
__device__ __forceinline__ float bf2f(unsigned short s) {
  unsigned u = ((unsigned)s) << 16;
  return __builtin_bit_cast(float, u);
}
__device__ __forceinline__ float fexp2(float x) { return __builtin_amdgcn_exp2f(x); }
__device__ __forceinline__ float frcp(float x) { return __builtin_amdgcn_rcpf(x); }
__device__ __forceinline__ float sigm(float x) {
  return frcp(1.0f + fexp2(-1.4426950408889634f * x));
}
__device__ __forceinline__ float tanha(float x) {
  return 1.0f - 2.0f * frcp(1.0f + fexp2(2.8853900817779268f * x));
}

__global__ __launch_bounds__(256) void cvt_f32_bf16(const float* __restrict__ in,
                                                    unsigned short* __restrict__ out,
                                                    int n8) {
  int i = blockIdx.x * 256 + threadIdx.x;
  if (i >= n8) return;
  const float4v* p = (const float4v*)in + (size_t)i * 2;
  float4v a = p[0], b = p[1];
  short8 v;
  v[0] = (short)f2bf(a[0]); v[1] = (short)f2bf(a[1]);
  v[2] = (short)f2bf(a[2]); v[3] = (short)f2bf(a[3]);
  v[4] = (short)f2bf(b[0]); v[5] = (short)f2bf(b[1]);
  v[6] = (short)f2bf(b[2]); v[7] = (short)f2bf(b[3]);
  ((short8*)out)[i] = v;
}

// Ax layouts: 0 = row-major [t][b][h] bf16 (layer5: xb); 1 = blocked
// [t][col>>3][b][col&7] bf16 (layer6: out5b; same layout as hbuf).
__global__ __launch_bounds__(256, 1) void lstm_layer(
    const unsigned short* __restrict__ Ax, const int xlayout,
    const float* __restrict__ wih, const float* __restrict__ whh,
    const float* __restrict__ bih, const float* __restrict__ bhh,
    const float* __restrict__ resf,          // fp32 row-major residual or null
    const unsigned short* __restrict__ resb, // bf16 blocked residual or null
    unsigned short* __restrict__ outb,       // bf16 blocked out or null
    float* __restrict__ outf,                // fp32 row-major out or null
    unsigned short* __restrict__ hbuf, int* __restrict__ flags) {
  const int p = blockIdx.x;
  const int tid = threadIdx.x;
  const int w = tid >> 6;
  const int lane = tid & 63;
  const int ln = lane & 15;
  const int q = lane >> 4;

  __shared__ float gp[4][BB][35];

  // ---- persistent weight fragments: this wave covers k in [256w, 256w+256)
  // wf[kk*2+nt]: n = 16*nt+ln, k = 256*w + kk*32 + 8*q + j
  short8 wfx[16], wfh[16];
#pragma unroll
  for (int kk = 0; kk < 8; ++kk) {
#pragma unroll
    for (int nt = 0; nt < 2; ++nt) {
      const int n = 16 * nt + ln;
      const int gidx = (n >> 3) * HH + p * 8 + (n & 7); // gate order i,f,g,o
      const int k0 = 256 * w + kk * 32 + 8 * q;
      const float* sx = wih + (size_t)gidx * HH + k0;
      const float* sh = whh + (size_t)gidx * HH + k0;
      short8 vx, vh;
#pragma unroll
      for (int j = 0; j < 8; ++j) { vx[j] = (short)f2bf(sx[j]); vh[j] = (short)f2bf(sh[j]); }
      wfx[kk * 2 + nt] = vx;
      wfh[kk * 2 + nt] = vh;
    }
  }

  // ---- elementwise state: thread owns (b=lane, cols 2w and 2w+1)
  const int eb = lane;
  const int jj0 = w;
  float bsum[2][4];
#pragma unroll
  for (int s = 0; s < 2; ++s) {
    const int jj = 2 * jj0 + s;
#pragma unroll
    for (int gt = 0; gt < 4; ++gt) {
      const int gidx = gt * HH + p * 8 + jj;
      bsum[s][gt] = bih[gidx] + bhh[gidx];
    }
  }
  float cst[2] = {0.f, 0.f};

  // ---- A-operand offsets
  size_t rh[4], rx[4], kx;
#pragma unroll
  for (int mt = 0; mt < 4; ++mt)
    rh[mt] = (size_t)(16 * mt + ln) * 8 + (size_t)(256 * w + 8 * q) * 64; // blocked
  if (xlayout == 0) {
    kx = 32;
#pragma unroll
    for (int mt = 0; mt < 4; ++mt)
      rx[mt] = (size_t)(16 * mt + ln) * HH + (size_t)(256 * w + 8 * q);
  } else {
    kx = 2048;
#pragma unroll
    for (int mt = 0; mt < 4; ++mt) rx[mt] = rh[mt];
  }

  for (int t = 0; t < TT; ++t) {
    float4v acc[4][2];
#pragma unroll
    for (int mt = 0; mt < 4; ++mt)
#pragma unroll
      for (int nt = 0; nt < 2; ++nt)
        acc[mt][nt] = (float4v){0.f, 0.f, 0.f, 0.f};

    // ---- x-part (no cross-WG dependency; overlaps other WGs' tails)
    {
      const unsigned short* Ab = Ax + (size_t)t * BH;
#pragma unroll
      for (int kk = 0; kk < 8; ++kk) {
        short8 af[4];
#pragma unroll
        for (int mt = 0; mt < 4; ++mt)
          af[mt] = *(const short8*)(Ab + rx[mt] + (size_t)kk * kx);
#pragma unroll
        for (int mt = 0; mt < 4; ++mt) {
          acc[mt][0] = __builtin_amdgcn_mfma_f32_16x16x32_bf16(af[mt], wfx[kk * 2 + 0], acc[mt][0], 0, 0, 0);
          acc[mt][1] = __builtin_amdgcn_mfma_f32_16x16x32_bf16(af[mt], wfx[kk * 2 + 1], acc[mt][1], 0, 0, 0);
        }
      }
    }

    // ---- h-part (gated on all 128 WGs having published h[t-1])
    if (t > 0) {
      if (w == 0) {
        int* fl = flags + (size_t)(t - 1) * GG;
        for (;;) {
          const int a0 = __hip_atomic_load(fl + lane, __ATOMIC_RELAXED, __HIP_MEMORY_SCOPE_AGENT);
          const int a1 = __hip_atomic_load(fl + 64 + lane, __ATOMIC_RELAXED, __HIP_MEMORY_SCOPE_AGENT);
          if (__all((a0 != 0) & (a1 != 0))) break;
          __builtin_amdgcn_s_sleep(2);
        }
      }
      __builtin_amdgcn_fence(__ATOMIC_ACQUIRE, "workgroup"); // compiler order only
      __syncthreads();
      const unsigned short* Hb = hbuf + (size_t)(t - 1) * BH;
#pragma unroll
      for (int kk = 0; kk < 8; ++kk) {
        short8 af[4];
#pragma unroll
        for (int mt = 0; mt < 4; ++mt)
          af[mt] = *(const short8*)(Hb + rh[mt] + (size_t)kk * 2048); // cached
#pragma unroll
        for (int mt = 0; mt < 4; ++mt) {
          acc[mt][0] = __builtin_amdgcn_mfma_f32_16x16x32_bf16(af[mt], wfh[kk * 2 + 0], acc[mt][0], 0, 0, 0);
          acc[mt][1] = __builtin_amdgcn_mfma_f32_16x16x32_bf16(af[mt], wfh[kk * 2 + 1], acc[mt][1], 0, 0, 0);
        }
      }
    }

    // C layout: row m = 16*mt + 4*q + r, col n = 16*nt + ln
#pragma unroll
    for (int mt = 0; mt < 4; ++mt)
#pragma unroll
      for (int nt = 0; nt < 2; ++nt)
#pragma unroll
        for (int r = 0; r < 4; ++r)
          gp[w][16 * mt + 4 * q + r][16 * nt + ln] = acc[mt][nt][r];

    __syncthreads();

    const size_t tb = (size_t)t * BH;
    const size_t hidx = tb + (size_t)p * 512 + (size_t)eb * 8 + 2 * jj0;
    float hv[2];
#pragma unroll
    for (int s = 0; s < 2; ++s) {
      const int jj = 2 * jj0 + s;
      float iv = bsum[s][0], fv = bsum[s][1], gv = bsum[s][2], ov = bsum[s][3];
#pragma unroll
      for (int ww = 0; ww < 4; ++ww) {
        iv += gp[ww][eb][jj];
        fv += gp[ww][eb][8 + jj];
        gv += gp[ww][eb][16 + jj];
        ov += gp[ww][eb][24 + jj];
      }
      const float ig = sigm(iv);
      const float fg = sigm(fv);
      const float gg_ = tanha(gv);
      const float og = sigm(ov);
      const float c = fg * cst[s] + ig * gg_;
      cst[s] = c;
      hv[s] = og * tanha(c);
    }
    // publish h first: packed 2xbf16 agent-scope 4B store -> LLC
    {
      unsigned packed = (unsigned)f2bf(hv[0]) | ((unsigned)f2bf(hv[1]) << 16);
      __hip_atomic_store((unsigned*)(hbuf + hidx), packed, __ATOMIC_RELAXED,
                         __HIP_MEMORY_SCOPE_AGENT);
    }
    asm volatile("s_waitcnt vmcnt(0)" ::: "memory"); // h store at coherent point
    __syncthreads();
    if (tid == 0)
      __hip_atomic_store(flags + (size_t)t * GG + p, 1, __ATOMIC_RELAXED,
                         __HIP_MEMORY_SCOPE_AGENT);

    // ---- output tail (off the inter-WG critical path)
    {
      float o0, o1;
      if (resf) {
        const float2v r = *(const float2v*)(resf + tb + (size_t)eb * HH + p * 8 + 2 * jj0);
        o0 = hv[0] + r[0];
        o1 = hv[1] + r[1];
      } else {
        const unsigned rb = *(const unsigned*)(resb + hidx);
        o0 = hv[0] + bf2f((unsigned short)(rb & 0xffff));
        o1 = hv[1] + bf2f((unsigned short)(rb >> 16));
      }
      if (outb)
        *(unsigned*)(outb + hidx) = (unsigned)f2bf(o0) | ((unsigned)f2bf(o1) << 16);
      if (outf) {
        float2v vo; vo[0] = o0; vo[1] = o1;
        *(float2v*)(outf + tb + (size_t)eb * HH + p * 8 + 2 * jj0) = vo;
      }
    }
  }
}

extern "C" void kernel_launch(void* const* d_in, const int* in_sizes, int n_in,
                              void* d_out, int out_size, void* d_ws, size_t ws_size,
                              hipStream_t stream) {
  const float* x    = (const float*)d_in[0];
  const float* wih5 = (const float*)d_in[1];
  const float* whh5 = (const float*)d_in[2];
  const float* bih5 = (const float*)d_in[3];
  const float* bhh5 = (const float*)d_in[4];
  const float* wih6 = (const float*)d_in[5];
  const float* whh6 = (const float*)d_in[6];
  const float* bih6 = (const float*)d_in[7];
  const float* bhh6 = (const float*)d_in[8];
  float* out = (float*)d_out;

  // ws (96.5 MB, same footprint as R2):
  //   [0,32M)   xb    : x bf16 row-major (layer5 input); REUSED as layer6 hbuf
  //   [32M,64M) out5b : layer5 output bf16 blocked (layer6 x-input + residual)
  //   [64M,96M) hbuf5 : layer5 h history bf16 blocked
  //   [96M,+256K) flags
  char* ws = (char*)d_ws;
  unsigned short* xb    = (unsigned short*)(ws);
  unsigned short* out5b = (unsigned short*)(ws + 33554432);
  unsigned short* hbuf5 = (unsigned short*)(ws + 67108864);
  int* flags            = (int*)(ws + 100663296);

  hipMemsetAsync(flags, 0, 2 * TT * GG * sizeof(int), stream);

  const int n8 = TT * BB * HH / 8;
  cvt_f32_bf16<<<dim3((n8 + 255) / 256), dim3(256), 0, stream>>>(x, xb, n8);

  lstm_layer<<<dim3(GG), dim3(256), 0, stream>>>(
      xb, 0, wih5, whh5, bih5, bhh5, x, nullptr, out5b, nullptr, hbuf5, flags);
  lstm_layer<<<dim3(GG), dim3(256), 0, stream>>>(
      out5b, 1, wih6, whh6, bih6, bhh6, nullptr, out5b, nullptr, out,
      xb /* layer6 hbuf */, flags + TT * GG);
}